// Round 6
// baseline (326.948 us; speedup 1.0000x reference)
//
#include <hip/hip_runtime.h>
#include <stdint.h>

#define NB 8
#define NC 256
#define NE 128
#define NHW 4096

typedef __bf16 v8bf __attribute__((ext_vector_type(8)));
typedef float v4f __attribute__((ext_vector_type(4)));
typedef float v16f __attribute__((ext_vector_type(16)));

#if __has_builtin(__builtin_amdgcn_exp2f)
#define EXP2F(x) __builtin_amdgcn_exp2f(x)
#else
#define EXP2F(x) exp2f(x)
#endif

// fp32 -> bf16 round-to-nearest-even (bit trick; finite inputs only)
__device__ __forceinline__ unsigned short f2bf(float x) {
    union { float f; unsigned int u; } v; v.f = x;
    unsigned int r = v.u + 0x7fffu + ((v.u >> 16) & 1u);
    return (unsigned short)(r >> 16);
}

// ---------------- K0: cast weights to bf16. Wbf[e][c], e<128 = w_theta * (scale*log2e), e>=128 = w_phi
__global__ __launch_bounds__(256) void cast_w_kernel(const float* __restrict__ wt,
                                                     const float* __restrict__ wp,
                                                     unsigned short* __restrict__ Wbf) {
    int i = blockIdx.x * 256 + threadIdx.x;                 // 0..65535
    const float QS = 0.08838834764831845f * 1.4426950408889634f; // 1/sqrt(128) * log2(e)
    float v = (i < 32768) ? wt[i] * QS : wp[i - 32768];
    Wbf[i] = f2bf(v);
}

// ---------------- K1: projection (+ fused V cast). Per block: batch b, 64-q tile.
// GEMM M=64(q) N=256(theta|phi) K=256(c); epilogue transposes through LDS so
// Q/K global stores are coalesced dwordx4 (R5's 2-byte scatter was ~4x waste).
__global__ __launch_bounds__(256, 2) void proj_kernel(const float* __restrict__ l,
                                                      const unsigned short* __restrict__ Wbf,
                                                      unsigned short* __restrict__ Qbf,
                                                      unsigned short* __restrict__ Kbf,
                                                      unsigned short* __restrict__ Vbf) {
    __shared__ __align__(16) unsigned short A[64][264];     // [q][c], +8 pad, 33792 B
    __shared__ __align__(16) unsigned short Ost[2][32][136];// out staging, 17408 B (51200 total)
    const int tid = threadIdx.x;
    const int b = blockIdx.x & 7;
    const int qt = (blockIdx.x >> 3) << 6;
    const float* lb = l + ((size_t)b * NC * NHW + qt);

    for (int s = 0; s < 16; ++s) {
        int f = tid + s * 256;
        int c = f >> 4, j = f & 15;
        float4 v = *(const float4*)(lb + (size_t)c * NHW + j * 4);
        ushort4 o4;
        o4.x = f2bf(v.x); o4.y = f2bf(v.y); o4.z = f2bf(v.z); o4.w = f2bf(v.w);
        A[j * 4 + 0][c] = o4.x;
        A[j * 4 + 1][c] = o4.y;
        A[j * 4 + 2][c] = o4.z;
        A[j * 4 + 3][c] = o4.w;
        *(ushort4*)(Vbf + (size_t)b * NC * NHW + (size_t)c * NHW + qt + j * 4) = o4;
    }
    __syncthreads();

    const int w = tid >> 6, L = tid & 63;
    const int l15 = L & 15, q4 = L >> 4;
    const v4f vz = {0.f, 0.f, 0.f, 0.f};
    v4f acc[4][4];
    for (int mt = 0; mt < 4; ++mt)
        for (int nt = 0; nt < 4; ++nt) acc[mt][nt] = vz;

    for (int kf = 0; kf < 8; ++kf) {
        int kc = kf * 32 + q4 * 8;
        v8bf a[4], bb[4];
        for (int mt = 0; mt < 4; ++mt)
            a[mt] = *(const v8bf*)&A[mt * 16 + l15][kc];
        for (int nt = 0; nt < 4; ++nt)
            bb[nt] = *(const v8bf*)(Wbf + (w * 64 + nt * 16 + l15) * 256 + kc);
        for (int mt = 0; mt < 4; ++mt)
            for (int nt = 0; nt < 4; ++nt)
                acc[mt][nt] = __builtin_amdgcn_mfma_f32_16x16x32_bf16(a[mt], bb[nt], acc[mt][nt], 0, 0, 0);
    }

    // epilogue: 2 phases of 32 q-rows; LDS transpose -> coalesced dwordx4 stores
    const int side = w >> 1;                                // 0 = Q (waves 0,1), 1 = K (waves 2,3)
    const int ebase = (w & 1) * 64;
#pragma unroll
    for (int ph = 0; ph < 2; ++ph) {
        __syncthreads();                                    // Ost WAR vs prev phase copy
#pragma unroll
        for (int mh = 0; mh < 2; ++mh) {
            int mt = ph * 2 + mh;
#pragma unroll
            for (int nt = 0; nt < 4; ++nt)
#pragma unroll
                for (int r = 0; r < 4; ++r) {
                    int q32 = mh * 16 + q4 * 4 + r;
                    Ost[side][q32][ebase + nt * 16 + l15] = f2bf(acc[mt][nt][r]);
                }
        }
        __syncthreads();                                    // Ost visible
#pragma unroll
        for (int s = 0; s < 4; ++s) {
            int idx = tid + s * 256;                        // 0..1023
            int sd = idx >> 9, rem = idx & 511;
            int r32 = rem >> 4, c8 = rem & 15;
            unsigned short* dst = sd ? Kbf : Qbf;
            *(uint4*)(dst + ((size_t)b * NHW + qt + ph * 32 + r32) * NE + c8 * 8) =
                *(const uint4*)&Ost[sd][r32][c8 * 8];
        }
    }
}

// ---------------- K2: flash attention, 32x32x16, q-tile 64, k-tile 64, 4 waves.
// NO K/V LDS staging: the MFMA fragment layouts are 16B-contiguous in global
// memory (bk = Kb[(k0+kcol)*NE + (2ef+hi)*8], av = Vb[c*NHW + k0 + (2kc+hi)*8]
// -- algebra unwound from R5's verified swizzle, identity transform), and the
// per-wave working set (K 8KB, V 16KB) is L1-resident. LDS carries only P.
// QK: wave (qh=w>>1, kh=w&1) -> S quarter, A=Q regs, B=K global frags.
// PV: wave owns c-tiles {2w,2w+1} x both q-tiles (V read once), A=V global
// frags, B=P^T from LDS. o = 64 AGPR. 2 barriers/iter (P WAR + visibility).
// LDS 8.7KB: Pu[64][64] xor8-swz (+ epilogue red overlay).
__global__ __launch_bounds__(256, 2) void attn_kernel(const unsigned short* __restrict__ Qbf,
                                                      const unsigned short* __restrict__ Kbf,
                                                      const unsigned short* __restrict__ Vbf,
                                                      float* __restrict__ out) {
    __shared__ __align__(16) unsigned char smem[8704];
    unsigned short* Pu = (unsigned short*)smem;             // [64][64] xor8-swz units
    float* red = (float*)smem;                              // epilogue overlay [4][32]

    const int tid = threadIdx.x;
    const int b = blockIdx.x & 7;                           // batch -> XCD affinity
    const int qt64 = (blockIdx.x >> 3) << 6;
    const int w = tid >> 6;
    const int L = tid & 63;
    const int l31 = L & 31, hi = L >> 5;
    const int qh = w >> 1, kh = w & 1;                      // QK roles
    const int kcol = kh * 32 + l31;

    const unsigned short* Kb = Kbf + (size_t)b * NHW * NE;
    const unsigned short* Vb = Vbf + (size_t)b * NC * NHW;

    // Q A-frags (whole kernel): A[m=q=l31][k=e], frag ef: e = ef*16 + hi*8 + j
    v8bf aq[8];
    {
        const unsigned short* qrow = Qbf + ((size_t)b * NHW + qt64 + qh * 32 + l31) * NE + hi * 8;
#pragma unroll
        for (int ef = 0; ef < 8; ++ef)
            aq[ef] = *(const v8bf*)(qrow + ef * 16);
    }

    v16f o[2][2];                                           // [ci][qt], 64 AGPR
#pragma unroll
    for (int ci = 0; ci < 2; ++ci)
#pragma unroll
        for (int qt = 0; qt < 2; ++qt)
#pragma unroll
            for (int r = 0; r < 16; ++r) o[ci][qt][r] = 0.f;
    float lacc[16];
#pragma unroll
    for (int r = 0; r < 16; ++r) lacc[r] = 0.f;

    for (int it = 0; it < 64; ++it) {
        const int k0 = it << 6;

        // ---- K B-frags direct from global (L1/L2); lanes l, l^32 read adjacent 16B
        v8bf bk[8];
        {
            const unsigned short* krow = Kb + (size_t)(k0 + kcol) * NE;
#pragma unroll
            for (int ef = 0; ef < 8; ++ef)
                bk[ef] = *(const v8bf*)(krow + (2 * ef + hi) * 8);
        }
        // ---- V A-frags direct from global (independent -> overlaps QK below)
        v8bf av[2][4];
#pragma unroll
        for (int ci = 0; ci < 2; ++ci) {
            const unsigned short* vrow = Vb + (size_t)((2 * w + ci) * 32 + l31) * NHW + k0;
#pragma unroll
            for (int kc = 0; kc < 4; ++kc)
                av[ci][kc] = *(const v8bf*)(vrow + (2 * kc + hi) * 8);
        }

        // ---- QK: S quarter [32q x 32k]; two 4-deep chains
        v16f sa, sb;
#pragma unroll
        for (int r = 0; r < 16; ++r) { sa[r] = 0.f; sb[r] = 0.f; }
#pragma unroll
        for (int ef = 0; ef < 4; ++ef) {
            sa = __builtin_amdgcn_mfma_f32_32x32x16_bf16(aq[ef], bk[ef], sa, 0, 0, 0);
            sb = __builtin_amdgcn_mfma_f32_32x32x16_bf16(aq[ef + 4], bk[ef + 4], sb, 0, 0, 0);
        }

        // ---- softmax: p = 2^s (scale*log2e folded into Q)
        float p[16];
#pragma unroll
        for (int r = 0; r < 16; ++r) p[r] = EXP2F(sa[r] + sb[r]);
#pragma unroll
        for (int r = 0; r < 16; ++r) lacc[r] += p[r];

        __syncthreads();                                    // B1: prev iter's P reads done
        // P scatter (C/D rows q = qh*32 + R(r)+4hi, col = kcol) -- R5-verified layout
#pragma unroll
        for (int r = 0; r < 16; ++r) {
            int q = qh * 32 + (r & 3) + 8 * (r >> 2) + 4 * hi;
            Pu[q * 64 + (((kcol >> 3) ^ (q & 7)) * 8) + (kcol & 7)] = f2bf(p[r]);
        }
        __syncthreads();                                    // B2: P visible

        // ---- PV: O^T tiles [32c x 32q]; A=V (global frags), B=P^T (LDS)
        v8bf bp[2][4];
#pragma unroll
        for (int qt = 0; qt < 2; ++qt) {
            int q = qt * 32 + l31;
            const unsigned short* prow = Pu + q * 64;
            int xq = q & 7;
#pragma unroll
            for (int kc = 0; kc < 4; ++kc)
                bp[qt][kc] = *(const v8bf*)(prow + (((kc * 2 + hi) ^ xq) * 8));
        }
#pragma unroll
        for (int kc = 0; kc < 4; ++kc)
#pragma unroll
            for (int qt = 0; qt < 2; ++qt)
#pragma unroll
                for (int ci = 0; ci < 2; ++ci)
                    o[ci][qt] = __builtin_amdgcn_mfma_f32_32x32x16_bf16(av[ci][kc], bp[qt][kc], o[ci][qt], 0, 0, 0);
    }
    __syncthreads();                                        // last P reads done; Pu reusable

    // ---- row sums: reduce over 32 k-cols (l31 lanes) per (qh,kh,hi) row set
#pragma unroll
    for (int r = 0; r < 16; ++r) {
        float v = lacc[r];
        v += __shfl_xor(v, 1);
        v += __shfl_xor(v, 2);
        v += __shfl_xor(v, 4);
        v += __shfl_xor(v, 8);
        v += __shfl_xor(v, 16);
        lacc[r] = v;
    }
    if (l31 == 0) {
#pragma unroll
        for (int r = 0; r < 16; ++r) {
            int q32 = (r & 3) + 8 * (r >> 2) + 4 * hi;
            red[(qh * 2 + kh) * 32 + q32] = lacc[r];
        }
    }
    __syncthreads();
    const float inv0 = 1.0f / (red[0 * 32 + l31] + red[1 * 32 + l31]);  // q-tile 0
    const float inv1 = 1.0f / (red[2 * 32 + l31] + red[3 * 32 + l31]);  // q-tile 1

    // ---- store: O^T C/D lane = q-col -> coalesced dword per (c,qt)
    float* ob = out + (size_t)b * NC * NHW + qt64 + l31;
#pragma unroll
    for (int ci = 0; ci < 2; ++ci)
#pragma unroll
        for (int r = 0; r < 16; ++r) {
            int c = (2 * w + ci) * 32 + (r & 3) + 8 * (r >> 2) + 4 * hi;
            ob[(size_t)c * NHW + 0] = o[ci][0][r] * inv0;
            ob[(size_t)c * NHW + 32] = o[ci][1][r] * inv1;
        }
}

extern "C" void kernel_launch(void* const* d_in, const int* in_sizes, int n_in,
                              void* d_out, int out_size, void* d_ws, size_t ws_size,
                              hipStream_t stream) {
    const float* l  = (const float*)d_in[0];
    const float* wt = (const float*)d_in[1];
    const float* wp = (const float*)d_in[2];
    float* out = (float*)d_out;

    char* ws = (char*)d_ws;
    unsigned short* Wbf = (unsigned short*)ws;                          // 131072 B
    unsigned short* Qbf = (unsigned short*)(ws + 131072);               // 8 MB
    unsigned short* Kbf = (unsigned short*)(ws + 131072 + 8388608);     // 8 MB
    unsigned short* Vbf = (unsigned short*)(ws + 131072 + 16777216);    // 16 MB

    hipLaunchKernelGGL(cast_w_kernel, dim3(256), dim3(256), 0, stream, wt, wp, Wbf);
    hipLaunchKernelGGL(proj_kernel,   dim3(512), dim3(256), 0, stream, l, Wbf, Qbf, Kbf, Vbf);
    hipLaunchKernelGGL(attn_kernel,   dim3(512), dim3(256), 0, stream, Qbf, Kbf, Vbf, out);
}

// Round 7
// 249.478 us; speedup vs baseline: 1.3105x; 1.3105x over previous
//
#include <hip/hip_runtime.h>
#include <stdint.h>

#define NB 8
#define NC 256
#define NE 128
#define NHW 4096

typedef __bf16 v8bf __attribute__((ext_vector_type(8)));
typedef float v4f __attribute__((ext_vector_type(4)));
typedef float v16f __attribute__((ext_vector_type(16)));

#if __has_builtin(__builtin_amdgcn_exp2f)
#define EXP2F(x) __builtin_amdgcn_exp2f(x)
#else
#define EXP2F(x) exp2f(x)
#endif

// LDS-only barrier: drains lgkmcnt (LDS) but NOT vmcnt -> global prefetch
// loads stay in flight across the barrier (CK/AITER idiom). __syncthreads
// would emit s_waitcnt vmcnt(0) and kill the software pipeline.
#define BARRIER_LDS() asm volatile("s_waitcnt lgkmcnt(0)\n\ts_barrier" ::: "memory")

// fp32 -> bf16 round-to-nearest-even (bit trick; finite inputs only)
__device__ __forceinline__ unsigned short f2bf(float x) {
    union { float f; unsigned int u; } v; v.f = x;
    unsigned int r = v.u + 0x7fffu + ((v.u >> 16) & 1u);
    return (unsigned short)(r >> 16);
}

// ---------------- K0: cast weights to bf16. Wbf[e][c], e<128 = w_theta * (scale*log2e), e>=128 = w_phi
__global__ __launch_bounds__(256) void cast_w_kernel(const float* __restrict__ wt,
                                                     const float* __restrict__ wp,
                                                     unsigned short* __restrict__ Wbf) {
    int i = blockIdx.x * 256 + threadIdx.x;                 // 0..65535
    const float QS = 0.08838834764831845f * 1.4426950408889634f; // 1/sqrt(128) * log2(e)
    float v = (i < 32768) ? wt[i] * QS : wp[i - 32768];
    Wbf[i] = f2bf(v);
}

// ---------------- K1: projection (+ fused V cast). Per block: batch b, 64-q tile.
__global__ __launch_bounds__(256, 2) void proj_kernel(const float* __restrict__ l,
                                                      const unsigned short* __restrict__ Wbf,
                                                      unsigned short* __restrict__ Qbf,
                                                      unsigned short* __restrict__ Kbf,
                                                      unsigned short* __restrict__ Vbf) {
    __shared__ __align__(16) unsigned short A[64][264];     // [q][c], +8 pad
    __shared__ __align__(16) unsigned short Ost[2][32][136];// out staging
    const int tid = threadIdx.x;
    const int b = blockIdx.x & 7;
    const int qt = (blockIdx.x >> 3) << 6;
    const float* lb = l + ((size_t)b * NC * NHW + qt);

    for (int s = 0; s < 16; ++s) {
        int f = tid + s * 256;
        int c = f >> 4, j = f & 15;
        float4 v = *(const float4*)(lb + (size_t)c * NHW + j * 4);
        ushort4 o4;
        o4.x = f2bf(v.x); o4.y = f2bf(v.y); o4.z = f2bf(v.z); o4.w = f2bf(v.w);
        A[j * 4 + 0][c] = o4.x;
        A[j * 4 + 1][c] = o4.y;
        A[j * 4 + 2][c] = o4.z;
        A[j * 4 + 3][c] = o4.w;
        *(ushort4*)(Vbf + (size_t)b * NC * NHW + (size_t)c * NHW + qt + j * 4) = o4;
    }
    __syncthreads();

    const int w = tid >> 6, L = tid & 63;
    const int l15 = L & 15, q4 = L >> 4;
    const v4f vz = {0.f, 0.f, 0.f, 0.f};
    v4f acc[4][4];
    for (int mt = 0; mt < 4; ++mt)
        for (int nt = 0; nt < 4; ++nt) acc[mt][nt] = vz;

    for (int kf = 0; kf < 8; ++kf) {
        int kc = kf * 32 + q4 * 8;
        v8bf a[4], bb[4];
        for (int mt = 0; mt < 4; ++mt)
            a[mt] = *(const v8bf*)&A[mt * 16 + l15][kc];
        for (int nt = 0; nt < 4; ++nt)
            bb[nt] = *(const v8bf*)(Wbf + (w * 64 + nt * 16 + l15) * 256 + kc);
        for (int mt = 0; mt < 4; ++mt)
            for (int nt = 0; nt < 4; ++nt)
                acc[mt][nt] = __builtin_amdgcn_mfma_f32_16x16x32_bf16(a[mt], bb[nt], acc[mt][nt], 0, 0, 0);
    }

    // epilogue: 2 phases of 32 q-rows; LDS transpose -> coalesced dwordx4 stores
    const int side = w >> 1;
    const int ebase = (w & 1) * 64;
#pragma unroll
    for (int ph = 0; ph < 2; ++ph) {
        __syncthreads();
#pragma unroll
        for (int mh = 0; mh < 2; ++mh) {
            int mt = ph * 2 + mh;
#pragma unroll
            for (int nt = 0; nt < 4; ++nt)
#pragma unroll
                for (int r = 0; r < 4; ++r) {
                    int q32 = mh * 16 + q4 * 4 + r;
                    Ost[side][q32][ebase + nt * 16 + l15] = f2bf(acc[mt][nt][r]);
                }
        }
        __syncthreads();
#pragma unroll
        for (int s = 0; s < 4; ++s) {
            int idx = tid + s * 256;
            int sd = idx >> 9, rem = idx & 511;
            int r32 = rem >> 4, c8 = rem & 15;
            unsigned short* dst = sd ? Kbf : Qbf;
            *(uint4*)(dst + ((size_t)b * NHW + qt + ph * 32 + r32) * NE + c8 * 8) =
                *(const uint4*)&Ost[sd][r32][c8 * 8];
        }
    }
}

// ---------------- K2: flash attention, 32x32x16, q-tile 64, k-tile 64, 4 waves.
// Pipelined with LDS-only barriers (vmcnt stays outstanding across s_barrier):
//   K: LDS-staged (swizzled); staging regs reloaded for tile i+1 right after
//      the tile-i LDS write -> one full iter of load slack.
//   V: global-direct reg A-frags (16B-contiguous layout, R6-verified);
//      reloaded for i+1 right after PV(i) consumes them -> ~full iter slack.
//   P: LDS round-trip (R5-verified scatter + R6-verified bp reads);
//      PV partition: wave owns c-tiles {2w,2w+1} x both q-tiles (V reuse 2x).
// LDS 24.5KB: Ku[64][128]xor16 (16K) | Pu[64][64]xor8 (8K, red overlay).
__global__ __launch_bounds__(256, 2) void attn_kernel(const unsigned short* __restrict__ Qbf,
                                                      const unsigned short* __restrict__ Kbf,
                                                      const unsigned short* __restrict__ Vbf,
                                                      float* __restrict__ out) {
    __shared__ __align__(16) unsigned char smem[24576];
    unsigned short* Ku = (unsigned short*)smem;             // [64][128] xor16-swz
    unsigned short* Pu = (unsigned short*)(smem + 16384);   // [64][64]  xor8-swz
    float* red = (float*)(smem + 16384);                    // epilogue overlay [4][32]

    const int tid = threadIdx.x;
    const int b = blockIdx.x & 7;                           // batch -> XCD affinity (L2-locks K/V per XCD)
    const int qt64 = (blockIdx.x >> 3) << 6;
    const int w = tid >> 6;
    const int L = tid & 63;
    const int l31 = L & 31, hi = L >> 5;
    const int qh = w >> 1, kh = w & 1;                      // QK roles
    const int kcol = kh * 32 + l31;
    const int x15 = kcol & 15;

    const unsigned short* Kb = Kbf + (size_t)b * NHW * NE;
    const unsigned short* Vb = Vbf + (size_t)b * NC * NHW;

    // Q A-frags (whole kernel): A[m=q=l31][k=e], frag ef: e = ef*16 + hi*8 + j
    v8bf aq[8];
    {
        const unsigned short* qrow = Qbf + ((size_t)b * NHW + qt64 + qh * 32 + l31) * NE + hi * 8;
#pragma unroll
        for (int ef = 0; ef < 8; ++ef)
            aq[ef] = *(const v8bf*)(qrow + ef * 16);
    }

    v16f o[2][2];                                           // [ci][qt], 64 AGPR
#pragma unroll
    for (int ci = 0; ci < 2; ++ci)
#pragma unroll
        for (int qt = 0; qt < 2; ++qt)
#pragma unroll
            for (int r = 0; r < 16; ++r) o[ci][qt][r] = 0.f;
    float lacc[16];
#pragma unroll
    for (int r = 0; r < 16; ++r) lacc[r] = 0.f;

    // V A-frag row bases: av[ci][kc] = vbase[ci] + k0 + kc*16  (R6-verified layout)
    const unsigned short* vbase0 = Vb + (size_t)((2 * w + 0) * 32 + l31) * NHW + hi * 8;
    const unsigned short* vbase1 = Vb + (size_t)((2 * w + 1) * 32 + l31) * NHW + hi * 8;

    // ---- prologue: K staging regs + V frags for tile 0
    const int r0 = tid >> 4, c8 = tid & 15;
    uint4 ks0 = *(const uint4*)(Kb + (size_t)(r0 + 0) * NE + c8 * 8);
    uint4 ks1 = *(const uint4*)(Kb + (size_t)(r0 + 16) * NE + c8 * 8);
    uint4 ks2 = *(const uint4*)(Kb + (size_t)(r0 + 32) * NE + c8 * 8);
    uint4 ks3 = *(const uint4*)(Kb + (size_t)(r0 + 48) * NE + c8 * 8);
    v8bf av[2][4];
#pragma unroll
    for (int kc = 0; kc < 4; ++kc) {
        av[0][kc] = *(const v8bf*)(vbase0 + kc * 16);
        av[1][kc] = *(const v8bf*)(vbase1 + kc * 16);
    }

    for (int it = 0; it < 64; ++it) {
        const int kn = ((it + 1) & 63) << 6;                // next tile offset
        BARRIER_LDS();                                      // B1: prev Ku/Pu reads done
        // write K tile i (swizzled), then immediately reload staging regs for i+1
        *(uint4*)&Ku[(r0 + 0) * 128 + ((c8 ^ ((r0 + 0) & 15)) * 8)] = ks0;
        *(uint4*)&Ku[(r0 + 16) * 128 + ((c8 ^ ((r0 + 16) & 15)) * 8)] = ks1;
        *(uint4*)&Ku[(r0 + 32) * 128 + ((c8 ^ ((r0 + 32) & 15)) * 8)] = ks2;
        *(uint4*)&Ku[(r0 + 48) * 128 + ((c8 ^ ((r0 + 48) & 15)) * 8)] = ks3;
        ks0 = *(const uint4*)(Kb + (size_t)(kn + r0 + 0) * NE + c8 * 8);
        ks1 = *(const uint4*)(Kb + (size_t)(kn + r0 + 16) * NE + c8 * 8);
        ks2 = *(const uint4*)(Kb + (size_t)(kn + r0 + 32) * NE + c8 * 8);
        ks3 = *(const uint4*)(Kb + (size_t)(kn + r0 + 48) * NE + c8 * 8);
        BARRIER_LDS();                                      // B2: Ku visible

        // ---- QK: S quarter [32q x 32k]; two 4-deep chains
        v16f sa, sb;
#pragma unroll
        for (int r = 0; r < 16; ++r) { sa[r] = 0.f; sb[r] = 0.f; }
        {
            const unsigned short* krow = Ku + kcol * 128;
#pragma unroll
            for (int ef = 0; ef < 4; ++ef) {
                v8bf bk0 = *(const v8bf*)(krow + (((2 * ef + hi) ^ x15) * 8));
                v8bf bk1 = *(const v8bf*)(krow + (((2 * (ef + 4) + hi) ^ x15) * 8));
                sa = __builtin_amdgcn_mfma_f32_32x32x16_bf16(aq[ef], bk0, sa, 0, 0, 0);
                sb = __builtin_amdgcn_mfma_f32_32x32x16_bf16(aq[ef + 4], bk1, sb, 0, 0, 0);
            }
        }

        // ---- softmax + P scatter (R5-verified layout)
        float p[16];
#pragma unroll
        for (int r = 0; r < 16; ++r) p[r] = EXP2F(sa[r] + sb[r]);
#pragma unroll
        for (int r = 0; r < 16; ++r) lacc[r] += p[r];
#pragma unroll
        for (int r = 0; r < 16; ++r) {
            int q = qh * 32 + (r & 3) + 8 * (r >> 2) + 4 * hi;
            Pu[q * 64 + (((kcol >> 3) ^ (q & 7)) * 8) + (kcol & 7)] = f2bf(p[r]);
        }
        BARRIER_LDS();                                      // B3: P visible

        // ---- PV: O^T tiles [32c x 32q]; A=V (regs, loaded last iter), B=P^T (LDS)
        v8bf bp[2][4];
#pragma unroll
        for (int qt = 0; qt < 2; ++qt) {
            int q = qt * 32 + l31;
            const unsigned short* prow = Pu + q * 64;
            int xq = q & 7;
#pragma unroll
            for (int kc = 0; kc < 4; ++kc)
                bp[qt][kc] = *(const v8bf*)(prow + (((kc * 2 + hi) ^ xq) * 8));
        }
#pragma unroll
        for (int kc = 0; kc < 4; ++kc)
#pragma unroll
            for (int qt = 0; qt < 2; ++qt) {
                o[0][qt] = __builtin_amdgcn_mfma_f32_32x32x16_bf16(av[0][kc], bp[qt][kc], o[0][qt], 0, 0, 0);
                o[1][qt] = __builtin_amdgcn_mfma_f32_32x32x16_bf16(av[1][kc], bp[qt][kc], o[1][qt], 0, 0, 0);
            }

        // ---- reload V frags for tile i+1 (consumed at next PV -> ~full iter slack)
#pragma unroll
        for (int kc = 0; kc < 4; ++kc) {
            av[0][kc] = *(const v8bf*)(vbase0 + kn + kc * 16);
            av[1][kc] = *(const v8bf*)(vbase1 + kn + kc * 16);
        }
    }
    BARRIER_LDS();                                          // last Pu reads done; overlay ok

    // ---- row sums: reduce over 32 k-cols (l31 lanes) per (qh,kh,hi) row set
#pragma unroll
    for (int r = 0; r < 16; ++r) {
        float v = lacc[r];
        v += __shfl_xor(v, 1);
        v += __shfl_xor(v, 2);
        v += __shfl_xor(v, 4);
        v += __shfl_xor(v, 8);
        v += __shfl_xor(v, 16);
        lacc[r] = v;
    }
    if (l31 == 0) {
#pragma unroll
        for (int r = 0; r < 16; ++r) {
            int q32 = (r & 3) + 8 * (r >> 2) + 4 * hi;
            red[(qh * 2 + kh) * 32 + q32] = lacc[r];
        }
    }
    BARRIER_LDS();
    const float inv0 = 1.0f / (red[0 * 32 + l31] + red[1 * 32 + l31]);  // q-tile 0
    const float inv1 = 1.0f / (red[2 * 32 + l31] + red[3 * 32 + l31]);  // q-tile 1

    // ---- store: O^T C/D lane = q-col -> coalesced dword per (c,qt)
    float* ob = out + (size_t)b * NC * NHW + qt64 + l31;
#pragma unroll
    for (int ci = 0; ci < 2; ++ci)
#pragma unroll
        for (int r = 0; r < 16; ++r) {
            int c = (2 * w + ci) * 32 + (r & 3) + 8 * (r >> 2) + 4 * hi;
            ob[(size_t)c * NHW + 0] = o[ci][0][r] * inv0;
            ob[(size_t)c * NHW + 32] = o[ci][1][r] * inv1;
        }
}

extern "C" void kernel_launch(void* const* d_in, const int* in_sizes, int n_in,
                              void* d_out, int out_size, void* d_ws, size_t ws_size,
                              hipStream_t stream) {
    const float* l  = (const float*)d_in[0];
    const float* wt = (const float*)d_in[1];
    const float* wp = (const float*)d_in[2];
    float* out = (float*)d_out;

    char* ws = (char*)d_ws;
    unsigned short* Wbf = (unsigned short*)ws;                          // 131072 B
    unsigned short* Qbf = (unsigned short*)(ws + 131072);               // 8 MB
    unsigned short* Kbf = (unsigned short*)(ws + 131072 + 8388608);     // 8 MB
    unsigned short* Vbf = (unsigned short*)(ws + 131072 + 16777216);    // 16 MB

    hipLaunchKernelGGL(cast_w_kernel, dim3(256), dim3(256), 0, stream, wt, wp, Wbf);
    hipLaunchKernelGGL(proj_kernel,   dim3(512), dim3(256), 0, stream, l, Wbf, Qbf, Kbf, Vbf);
    hipLaunchKernelGGL(attn_kernel,   dim3(512), dim3(256), 0, stream, Qbf, Kbf, Vbf, out);
}